// Round 11
// baseline (434.552 us; speedup 1.0000x reference)
//
#include <hip/hip_runtime.h>
#include <stdint.h>

#define N_P 100000
#define N_D 50000
#define NE  600000
#define F   128
#define FP  136   // padded LDS/global row stride (272B = 17*16B: 16B-aligned, 2-way-free banks)

// counting-sort build params (u16 global hist, NCHK=32, HPH=4)
#define NCHK   32
#define CHKE   18752                 // edges per chunk (mult of 4); last chunk = 18688
#define HPH    4                     // hist partitions (u16-packed LDS -> 50 KB)
// R11 scatter partitions: pd=8 (N_D/8=6250), dp=16 (N_P/16=6250) -> both 25 KB
#define HPS_PD 8
#define HPS_DP 16
#define SPART  6250                  // cursor ints per scatter block (25 KB)
// hist layout (u16 elements): A0 pd_src[32][N_P] | A1 pd_dst[32][N_D] | A2 dp_src[32][N_D] | A3 dp_dst[32][N_P]
#define HOFS_A0 ((size_t)0)
#define HOFS_A1 ((size_t)NCHK*N_P)
#define HOFS_A2 ((size_t)NCHK*N_P + (size_t)NCHK*N_D)
#define HOFS_A3 ((size_t)NCHK*N_P + (size_t)2*NCHK*N_D)
// convert work units ("blocks" of 256 threads)
#define CVT_TOT (6 + (N_P+N_D)*F/4/256)   // 6 + 18750 = 18756
#define NBA 98    // scan tiles over N_D (512 nodes each)
#define NBB 196   // scan tiles over N_P
// sumdeg tiling: 256 node-pairs (=512 nodes) per block, 4 arrays
#define SD_T0 196  // arr0 (N_P) tiles
#define SD_T1 98   // arr1 (N_D)
#define SD_T2 98   // arr2 (N_D)
#define SD_T3 196  // arr3 (N_P)
#define NSCAT (HPS_PD*NCHK + HPS_DP*NCHK)   // 256 + 512 = 768 scatter blocks

typedef __attribute__((ext_vector_type(8))) __bf16 bf16x8;
typedef __attribute__((ext_vector_type(4))) float  f32x4;

static __device__ __forceinline__ float bf2f(uint16_t u){
  union{float f;uint32_t i;} v; v.i = ((uint32_t)u)<<16; return v.f;
}
static __device__ __forceinline__ uint16_t f2bf(float f){
  union{float f;uint32_t i;} v; v.f = f;
  uint32_t i = v.i;
  uint32_t r = i + 0x7fffu + ((i>>16)&1u);   // round-to-nearest-even
  return (uint16_t)(r>>16);
}

// ---------------- phase 1: per-(array, part, chunk) LDS histogram -----------
// grid = 4*HPH*NCHK = 512 blocks x 512 thr. u16-packed counts in LDS AND in
// global (per-chunk count < 2^16). LDS atomics (R3: global atomics 100us).
__global__ __launch_bounds__(512) void k_hist(
    const int* __restrict__ pd_src, const int* __restrict__ pd_dst,
    const int* __restrict__ dp_src, const int* __restrict__ dp_dst,
    uint16_t* __restrict__ hist){
  __shared__ uint32_t cnt[(N_P/HPH)/2];   // 12500 words = 50 KB
  const int b = blockIdx.x;
  const int arr = b >> 7, part = (b >> 5) & 3, chunk = b & 31;
  const int* src; int N; size_t hofs;
  switch(arr){
    case 0:  src = pd_src; N = N_P; hofs = HOFS_A0; break;
    case 1:  src = pd_dst; N = N_D; hofs = HOFS_A1; break;
    case 2:  src = dp_src; N = N_D; hofs = HOFS_A2; break;
    default: src = dp_dst; N = N_P; hofs = HOFS_A3; break;
  }
  const int PART = N / HPH;
  const int nw   = PART >> 1;
  const int lo   = part * PART;
  for (int i = threadIdx.x; i < nw; i += 512) cnt[i] = 0;
  __syncthreads();
  const int e0 = chunk*CHKE, e1 = min(e0 + CHKE, NE);
  const uint4* s4 = (const uint4*)(src + e0);
  const int n4 = (e1 - e0) >> 2;
  for (int i = threadIdx.x; i < n4; i += 512){
    uint4 v = s4[i];
    int a0 = (int)v.x - lo, a1 = (int)v.y - lo, a2 = (int)v.z - lo, a3 = (int)v.w - lo;
    if ((unsigned)a0 < (unsigned)PART) atomicAdd(&cnt[a0>>1], 1u << ((a0&1)<<4));
    if ((unsigned)a1 < (unsigned)PART) atomicAdd(&cnt[a1>>1], 1u << ((a1&1)<<4));
    if ((unsigned)a2 < (unsigned)PART) atomicAdd(&cnt[a2>>1], 1u << ((a2&1)<<4));
    if ((unsigned)a3 < (unsigned)PART) atomicAdd(&cnt[a3>>1], 1u << ((a3&1)<<4));
  }
  __syncthreads();
  uint32_t* out32 = (uint32_t*)(hist + hofs + (size_t)chunk*N + lo);
  for (int i = threadIdx.x; i < nw; i += 512) out32[i] = cnt[i];
}

// ------- phase 2: sumdeg + rs + FUSED scan1 (per-tile sums) -----------------
// one block per 256 node-pairs (=512 nodes) of one array; block == scan tile,
// so the in-degree tile sums reduce directly into bsums (kills scan1 launch).
__global__ __launch_bounds__(256) void k_sumdeg2(
    uint16_t* __restrict__ hist,
    int* __restrict__ cnt_d_in, int* __restrict__ cnt_p_in,
    float* __restrict__ rs_p_out, float* __restrict__ rs_p_in,
    float* __restrict__ rs_d_out, float* __restrict__ rs_d_in,
    int* __restrict__ bsums){
  __shared__ int red[4];
  const int b = blockIdx.x, t = threadIdx.x;
  int arr, tile;
  if      (b < SD_T0)            { arr = 0; tile = b; }
  else if (b < SD_T0+SD_T1)      { arr = 1; tile = b - SD_T0; }
  else if (b < SD_T0+SD_T1+SD_T2){ arr = 2; tile = b - SD_T0 - SD_T1; }
  else                           { arr = 3; tile = b - SD_T0 - SD_T1 - SD_T2; }
  int N; size_t hofs; bool pre;
  switch(arr){
    case 0:  N = N_P; hofs = HOFS_A0; pre = false; break;
    case 1:  N = N_D; hofs = HOFS_A1; pre = true;  break;
    case 2:  N = N_D; hofs = HOFS_A2; pre = false; break;
    default: N = N_P; hofs = HOFS_A3; pre = true;  break;
  }
  const int npair = N >> 1;
  const int pidx  = tile*256 + t;
  int run0 = 0, run1 = 0;
  if (pidx < npair){
    uint32_t* h32 = (uint32_t*)(hist + hofs) + pidx;
    const int stride = npair;
    if (pre){
      #pragma unroll 4
      for (int c = 0; c < NCHK; ++c){
        uint32_t w = h32[(size_t)c*stride];
        h32[(size_t)c*stride] = (uint32_t)run0 | ((uint32_t)run1 << 16);
        run0 += (int)(w & 0xffffu); run1 += (int)(w >> 16);
      }
    } else {
      #pragma unroll 4
      for (int c = 0; c < NCHK; ++c){
        uint32_t w = h32[(size_t)c*stride];
        run0 += (int)(w & 0xffffu); run1 += (int)(w >> 16);
      }
    }
    const int idx = 2*pidx;
    float rs0 = rsqrtf((float)max(run0, 1));
    float rs1 = rsqrtf((float)max(run1, 1));
    switch(arr){
      case 0:  rs_p_out[idx] = rs0; rs_p_out[idx+1] = rs1; break;
      case 1:  cnt_d_in[idx] = run0; cnt_d_in[idx+1] = run1;
               rs_d_in[idx] = rs0;  rs_d_in[idx+1] = rs1;  break;
      case 2:  rs_d_out[idx] = rs0; rs_d_out[idx+1] = rs1; break;
      default: cnt_p_in[idx] = run0; cnt_p_in[idx+1] = run1;
               rs_p_in[idx] = rs0;  rs_p_in[idx+1] = rs1;  break;
    }
  }
  if (arr == 1 || arr == 3){
    int s = run0 + run1;               // 0 for out-of-range pairs
    #pragma unroll
    for (int o = 32; o; o >>= 1) s += __shfl_down(s, o, 64);
    if ((t & 63) == 0) red[t >> 6] = s;
    __syncthreads();
    if (t == 0){
      int tot = red[0] + red[1] + red[2] + red[3];
      bsums[(arr == 1) ? tile : 256 + tile] = tot;
    }
  }
}

// ------- scan3: inline scan2 (each block scans bsums seg in LDS) ------------
__global__ __launch_bounds__(512) void k_scan3b(
    const int* __restrict__ cA, int nA,
    const int* __restrict__ cB, int nB,
    const int* __restrict__ bsums,
    int* __restrict__ offA, int* __restrict__ offB){
  __shared__ int sh[512];
  __shared__ int sb[256];
  __shared__ int base_s;
  int b = blockIdx.x, t = threadIdx.x;
  const int* in; int n, bi; int* out; int seg, nb;
  if (b < NBA){ in = cA; n = nA; bi = b;       out = offA; seg = 0; nb = NBA; }
  else        { in = cB; n = nB; bi = b - NBA; out = offB; seg = 1; nb = NBB; }
  // inline inclusive scan of the bsums segment (<=256 elems); bsums unmodified
  int v0 = 0;
  if (t < 256){ v0 = (t < nb) ? bsums[seg*256 + t] : 0; sb[t] = v0; }
  __syncthreads();
  for (int ofs = 1; ofs < 256; ofs <<= 1){
    int u = 0;
    if (t < 256 && t >= ofs) u = sb[t-ofs];
    __syncthreads();
    if (t < 256) sb[t] += u;
    __syncthreads();
  }
  if (t == 0) base_s = (bi == 0) ? 0 : sb[bi-1];   // exclusive prefix
  __syncthreads();
  const int base = base_s;
  // 512-wide tile scan
  int i = bi*512 + t;
  int v = (i < n) ? in[i] : 0;
  sh[t] = v; __syncthreads();
  for (int ofs = 1; ofs < 512; ofs <<= 1){
    int u = (t >= ofs) ? sh[t-ofs] : 0; __syncthreads();
    sh[t] += u; __syncthreads();
  }
  if (i < n) out[i] = base + sh[t] - v;
  if (b == 0 && t == 0){ offA[nA] = NE; offB[nB] = NE; }
}

// ---- convert work unit: ob<6 = weight transpose + sentinel; else features ----
static __device__ __forceinline__ void convert_ob(
    int ob, int t,
    const float4* __restrict__ hp, const float4* __restrict__ hd,
    const float* __restrict__ rs_po, const float* __restrict__ rs_do,
    uint2* __restrict__ P0, uint2* __restrict__ D0,
    const float* w0,const float* w1,const float* w2,
    const float* w3,const float* w4,const float* w5,
    uint16_t* __restrict__ wt,
    uint16_t* z0, uint16_t* z1, uint16_t* z2,
    uint16_t* z3, uint16_t* z4, uint16_t* z5)
{
  if (ob < 6){
    const float* W; uint16_t* Z;
    switch(ob){ case 0:W=w0;Z=z0;break; case 1:W=w1;Z=z1;break; case 2:W=w2;Z=z2;break;
                case 3:W=w3;Z=z3;break; case 4:W=w4;Z=z4;break; default:W=w5;Z=z5; }
    uint16_t* T = wt + ob*F*FP;
    for (int idx = t; idx < F*F; idx += 256){
      int k = idx >> 7, j = idx & 127;
      T[j*FP + k] = f2bf(W[idx]);
    }
    if (t < F) Z[t] = 0;   // sentinel zero row
    return;
  }
  int i = (ob - 6)*256 + t;
  const int nP4 = N_P*F/4, nD4 = N_D*F/4;
  if (i < nP4){
    float4 v = hp[i]; float s = rs_po[i >> 5];
    uint2 r;
    r.x = ((uint32_t)f2bf(v.y*s)<<16) | f2bf(v.x*s);
    r.y = ((uint32_t)f2bf(v.w*s)<<16) | f2bf(v.z*s);
    P0[i] = r;
  } else {
    int j = i - nP4;
    if (j < nD4){
      float4 v = hd[j]; float s = rs_do[j >> 5];
      uint2 r;
      r.x = ((uint32_t)f2bf(v.y*s)<<16) | f2bf(v.x*s);
      r.y = ((uint32_t)f2bf(v.w*s)<<16) | f2bf(v.z*s);
      D0[j] = r;
    }
  }
}

// ------- phase 3 (R11): scatter FUSED with convert, 25 KB cursors -----------
// R10's 50 KB cursor LDS capped the WHOLE fused kernel at 3 blk/CU (occ 30%,
// scatter tail = critical path for all 81us). R11: pd keeps HPS=8
// (N_D/8=6250 ints), dp goes HPS=16 (N_P/16=6250 ints) -> both 25 KB ->
// 6 blk/CU; 768 scatter blocks w/ halved dp atomic work each. dp edge
// re-reads double (+38 MB, L2-absorbed: 16 siblings share each 150 KB chunk).
// N_D/16=3125 is odd (breaks u32-paired cursor init) — hence the split HPS.
__global__ __launch_bounds__(512) void k_scatter_cvt(
    const int* __restrict__ pd_src, const int* __restrict__ pd_dst,
    const int* __restrict__ dp_src, const int* __restrict__ dp_dst,
    const int* __restrict__ off_pd, const int* __restrict__ off_dp,
    const uint16_t* __restrict__ hist,
    int* __restrict__ col_pd, int* __restrict__ col_dp,
    const float4* __restrict__ hp, const float4* __restrict__ hd,
    const float* __restrict__ rs_po, const float* __restrict__ rs_do,
    uint2* __restrict__ P0, uint2* __restrict__ D0,
    const float* w0,const float* w1,const float* w2,
    const float* w3,const float* w4,const float* w5,
    uint16_t* __restrict__ wt,
    uint16_t* z0, uint16_t* z1, uint16_t* z2,
    uint16_t* z3, uint16_t* z4, uint16_t* z5){
  __shared__ int base[SPART];   // 6250 ints = 25 KB -> 6 blocks/CU
  const int b = blockIdx.x;
  if (b >= NSCAT){
    const int ob = (b - NSCAT)*2 + (threadIdx.x >> 8);
    if (ob < CVT_TOT)
      convert_ob(ob, threadIdx.x & 255, hp, hd, rs_po, rs_do, P0, D0,
                 w0,w1,w2,w3,w4,w5, wt, z0,z1,z2,z3,z4,z5);
    return;
  }
  const int* dsts; const int* srcs; const int* off; int* col; int N; size_t hofs;
  int part, chunk;
  if (b < HPS_PD*NCHK){          // pd phase: 256 blocks, HPS=8
    part = (b >> 5) & 7; chunk = b & 31;
    dsts = pd_dst; srcs = pd_src; off = off_pd; col = col_pd; N = N_D; hofs = HOFS_A1;
  } else {                       // dp phase: 512 blocks, HPS=16
    const int bb = b - HPS_PD*NCHK;
    part = (bb >> 5) & 15; chunk = bb & 31;
    dsts = dp_dst; srcs = dp_src; off = off_dp; col = col_dp; N = N_P; hofs = HOFS_A3;
  }
  const int PART = SPART;        // 6250 both phases
  const int lo = part * PART;    // even (PART even) -> u32-paired hist reads OK
  const uint32_t* hc32 = (const uint32_t*)(hist + hofs + (size_t)chunk*N + lo);
  const int* offp = off + lo;
  for (int i = threadIdx.x; i < (PART>>1); i += 512){
    uint32_t w = hc32[i];
    base[2*i]   = offp[2*i]   + (int)(w & 0xffffu);
    base[2*i+1] = offp[2*i+1] + (int)(w >> 16);
  }
  __syncthreads();
  const int e0 = chunk*CHKE, e1 = min(e0 + CHKE, NE);
  const uint4* d4 = (const uint4*)(dsts + e0);
  const int n4 = (e1 - e0) >> 2;
  for (int i = threadIdx.x; i < n4; i += 512){
    uint4 d = d4[i];
    int a0 = (int)d.x - lo, a1 = (int)d.y - lo, a2 = (int)d.z - lo, a3 = (int)d.w - lo;
    int e = e0 + 4*i;
    if ((unsigned)a0 < (unsigned)PART){ int p = atomicAdd(&base[a0], 1); col[p] = srcs[e+0]; }
    if ((unsigned)a1 < (unsigned)PART){ int p = atomicAdd(&base[a1], 1); col[p] = srcs[e+1]; }
    if ((unsigned)a2 < (unsigned)PART){ int p = atomicAdd(&base[a2], 1); col[p] = srcs[e+2]; }
    if ((unsigned)a3 < (unsigned)PART){ int p = atomicAdd(&base[a3], 1); col[p] = srcs[e+3]; }
  }
}

// ---------------- fused gconv PAIR (R1/R4 gather, R9 2-pass GEMM) -----------
// Gather: wave = 4 groups of 16 lanes; group g owns a row, lane l holds
// features [8l,8l+8). Broadcast all 16 col indices up front, issue ALL 8
// (16 when deg>8) plain uint4 gather loads into register arrays, THEN
// accumulate. (256,4) bounds. Counter-backed reversions: no nt loads (FETCH
// +9MB), no LDS epilogue (WRITE 75MB = layer-3 logical), no dual-stream.
// 2-pass GEMM (4 acc tiles/pass, per-pass epilogue, #pragma unroll 1) halves
// live AGPRs; R10 showed no regression (gconv fell below top-5 cutoff).
template<int OUT_MODE>
__global__ __launch_bounds__(256, 4) void k_gconv2(
    const uint16_t* __restrict__ xA, const int* __restrict__ offAp, const int* __restrict__ colA,
    const float* __restrict__ rsA, const uint16_t* __restrict__ WtA, const float* __restrict__ biasA,
    const float* __restrict__ rsnA, void* __restrict__ outA, int ndA, int nsA, int nblkA,
    const uint16_t* __restrict__ xB, const int* __restrict__ offBp, const int* __restrict__ colB,
    const float* __restrict__ rsB, const uint16_t* __restrict__ WtB, const float* __restrict__ biasB,
    const float* __restrict__ rsnB, void* __restrict__ outB, int ndB, int nsB)
{
  __shared__ uint16_t m_lds[64*FP];    // 17408 B
  const int tid  = threadIdx.x;
  const int lane = tid & 63;
  const int wv   = tid >> 6;

  const uint16_t* x; const int* off; const int* col; const float* rs_in;
  const uint16_t* Wt; const float* bias; const float* rs_next; void* outp;
  int n_dst, zrow, bid;
  if ((int)blockIdx.x < nblkA){
    x = xA; off = offAp; col = colA; rs_in = rsA; Wt = WtA; bias = biasA;
    rs_next = rsnA; outp = outA; n_dst = ndA; zrow = nsA; bid = blockIdx.x;
  } else {
    x = xB; off = offBp; col = colB; rs_in = rsB; Wt = WtB; bias = biasB;
    rs_next = rsnB; outp = outB; n_dst = ndB; zrow = nsB; bid = blockIdx.x - nblkA;
  }

  // ---- aggregation ----
  const int row0 = bid*64 + wv*16;
  const int g    = lane >> 4;     // group
  const int l    = lane & 15;     // lane in group; features [8l, 8l+8)
  const uint16_t* xl = x + l*8;   // lane-fixed feature slice base

  int e0a[4], e1a[4], cva[4];
  #pragma unroll
  for (int i = 0; i < 4; ++i){
    int r = row0 + i*4 + g;
    bool rv = r < n_dst;
    e0a[i] = rv ? off[r]   : 0;
    e1a[i] = rv ? off[r+1] : 0;
  }
  #pragma unroll
  for (int i = 0; i < 4; ++i){
    int last = (e1a[i] > 0) ? e1a[i]-1 : 0;
    int idx  = e0a[i] + l;
    cva[i] = col[idx < e1a[i] ? idx : last];   // hoisted first batch (4 loads in flight)
  }

  #pragma unroll
  for (int i = 0; i < 4; ++i){
    int e0 = e0a[i], e1 = e1a[i];
    int cv = cva[i];
    float a0=0.f,a1=0.f,a2=0.f,a3=0.f,a4=0.f,a5=0.f,a6=0.f,a7=0.f;
    for (int e = e0; e < e1; e += 16){
      // prefetch next batch of col indices (clamped; harmless L1 re-read)
      int nidx = e + 16 + l;
      int ncv  = col[nidx < e1 ? nidx : e1-1];
      int cnt  = e1 - e;
      const bool more = (cnt > 8);
      // broadcast col indices for the whole batch up front (VALU/LDS only)
      int cb[16];
      #pragma unroll
      for (int q = 0; q < 8; ++q) cb[q] = __shfl(cv, g*16 + q, 64);
      if (more){
        #pragma unroll
        for (int q = 8; q < 16; ++q) cb[q] = __shfl(cv, g*16 + q, 64);
      }
      // issue ALL gather loads before any accumulation (max MLP)
      uint4 u[8], w[8];
      #pragma unroll
      for (int q = 0; q < 8; ++q){
        int c = (q < cnt) ? cb[q] : zrow;        // sentinel row = zeros
        u[q] = *(const uint4*)(xl + (size_t)c*F);
      }
      if (more){
        #pragma unroll
        for (int q = 8; q < 16; ++q){
          int c = (q < cnt) ? cb[q] : zrow;
          w[q-8] = *(const uint4*)(xl + (size_t)c*F);
        }
      }
      // accumulate
      #pragma unroll
      for (int q = 0; q < 8; ++q){
        a0 += bf2f((uint16_t)u[q].x); a1 += bf2f((uint16_t)(u[q].x>>16));
        a2 += bf2f((uint16_t)u[q].y); a3 += bf2f((uint16_t)(u[q].y>>16));
        a4 += bf2f((uint16_t)u[q].z); a5 += bf2f((uint16_t)(u[q].z>>16));
        a6 += bf2f((uint16_t)u[q].w); a7 += bf2f((uint16_t)(u[q].w>>16));
      }
      if (more){
        #pragma unroll
        for (int q = 0; q < 8; ++q){
          a0 += bf2f((uint16_t)w[q].x); a1 += bf2f((uint16_t)(w[q].x>>16));
          a2 += bf2f((uint16_t)w[q].y); a3 += bf2f((uint16_t)(w[q].y>>16));
          a4 += bf2f((uint16_t)w[q].z); a5 += bf2f((uint16_t)(w[q].z>>16));
          a6 += bf2f((uint16_t)w[q].w); a7 += bf2f((uint16_t)(w[q].w>>16));
        }
      }
      cv = ncv;
    }
    int r = row0 + i*4 + g;
    float rs = (r < n_dst) ? rs_in[r] : 0.f;
    uint4 pk;
    pk.x = ((uint32_t)f2bf(a1*rs)<<16) | f2bf(a0*rs);
    pk.y = ((uint32_t)f2bf(a3*rs)<<16) | f2bf(a2*rs);
    pk.z = ((uint32_t)f2bf(a5*rs)<<16) | f2bf(a4*rs);
    pk.w = ((uint32_t)f2bf(a7*rs)<<16) | f2bf(a6*rs);
    *(uint4*)&m_lds[(wv*16 + i*4 + g)*FP + l*8] = pk;
  }
  // no barrier: m_lds rows are wave-private, same-wave ds ordering is implicit

  // ---- GEMM (operand-swapped), 2 passes of 4 tiles to halve live AGPRs ----
  const int mrow = lane & 15;
  const int kgrp = lane >> 4;
  const int q4 = kgrp * 4;
  const int rr = row0 + mrow;
  const bool rv = rr < n_dst;
  const float rsn = (OUT_MODE == 0) ? (rv ? rs_next[rr] : 0.f) : 1.f;
  #pragma unroll 1
  for (int pass = 0; pass < 2; ++pass){
    f32x4 acc[4];
    #pragma unroll
    for (int t = 0; t < 4; ++t) acc[t] = (f32x4){0.f,0.f,0.f,0.f};
    #pragma unroll
    for (int k0 = 0; k0 < F; k0 += 32){
      bf16x8 bfrag = *(const bf16x8*)&m_lds[(wv*16 + mrow)*FP + k0 + kgrp*8];
      #pragma unroll
      for (int t = 0; t < 4; ++t){
        bf16x8 afrag = *(const bf16x8*)&Wt[((pass*4 + t)*16 + mrow)*FP + k0 + kgrp*8];
        acc[t] = __builtin_amdgcn_mfma_f32_16x16x32_bf16(afrag, bfrag, acc[t], 0, 0, 0);
      }
    }
    if (rv){
      #pragma unroll
      for (int t = 0; t < 4; ++t){
        const int tp = pass*4 + t;
        float4 b4 = *(const float4*)&bias[tp*16 + q4];
        float v0 = fmaxf(acc[t][0] + b4.x, 0.f);
        float v1 = fmaxf(acc[t][1] + b4.y, 0.f);
        float v2 = fmaxf(acc[t][2] + b4.z, 0.f);
        float v3 = fmaxf(acc[t][3] + b4.w, 0.f);
        if (OUT_MODE == 0){
          uint2 pk;
          pk.x = ((uint32_t)f2bf(v1*rsn)<<16) | f2bf(v0*rsn);
          pk.y = ((uint32_t)f2bf(v3*rsn)<<16) | f2bf(v2*rsn);
          *(uint2*)((uint16_t*)outp + (size_t)rr*F + tp*16 + q4) = pk;
        } else {
          float4 o; o.x = v0; o.y = v1; o.z = v2; o.w = v3;
          *(float4*)((float*)outp + (size_t)rr*F + tp*16 + q4) = o;
        }
      }
    }
  }
}

extern "C" void kernel_launch(void* const* d_in, const int* in_sizes, int n_in,
                              void* d_out, int out_size, void* d_ws, size_t ws_size,
                              hipStream_t stream) {
  const float* h_p   = (const float*)d_in[0];
  const float* h_d   = (const float*)d_in[1];
  const int* pd_src  = (const int*)d_in[2];
  const int* pd_dst  = (const int*)d_in[3];
  const int* dp_src  = (const int*)d_in[4];
  const int* dp_dst  = (const int*)d_in[5];
  const float* W1_pd = (const float*)d_in[6];   const float* b1_pd = (const float*)d_in[7];
  const float* W1_dp = (const float*)d_in[8];   const float* b1_dp = (const float*)d_in[9];
  const float* W2_pd = (const float*)d_in[10];  const float* b2_pd = (const float*)d_in[11];
  const float* W2_dp = (const float*)d_in[12];  const float* b2_dp = (const float*)d_in[13];
  const float* W3_pd = (const float*)d_in[14];  const float* b3_pd = (const float*)d_in[15];
  const float* W3_dp = (const float*)d_in[16];  const float* b3_dp = (const float*)d_in[17];

  char* w = (char*)d_ws;
  size_t o = 0;
  auto take = [&](size_t bytes)->char*{
    char* p = w + o; o += (bytes + 255) & ~(size_t)255; return p;
  };

  int* cnt_d_in  = (int*)take(4*(size_t)N_D);
  int* cnt_p_in  = (int*)take(4*(size_t)N_P);
  int* off_pd   = (int*)take(4*(size_t)(N_D+1));
  int* off_dp   = (int*)take(4*(size_t)(N_P+1));
  int* bsums    = (int*)take(4*512);
  int* col_pd   = (int*)take(4*(size_t)NE);
  int* col_dp   = (int*)take(4*(size_t)NE);
  float* rs_p_out = (float*)take(4*(size_t)N_P);
  float* rs_p_in  = (float*)take(4*(size_t)N_P);
  float* rs_d_out = (float*)take(4*(size_t)N_D);
  float* rs_d_in  = (float*)take(4*(size_t)N_D);
  uint16_t* wt  = (uint16_t*)take(2*(size_t)6*F*FP);
  // feature buffers have n+1 rows; row n is the zeroed sentinel
  uint16_t* P0  = (uint16_t*)take(2*(size_t)(N_P+1)*F);
  uint16_t* P1  = (uint16_t*)take(2*(size_t)(N_P+1)*F);
  uint16_t* P2  = (uint16_t*)take(2*(size_t)(N_P+1)*F);
  uint16_t* D0  = (uint16_t*)take(2*(size_t)(N_D+1)*F);
  uint16_t* D1  = (uint16_t*)take(2*(size_t)(N_D+1)*F);
  uint16_t* D2  = (uint16_t*)take(2*(size_t)(N_D+1)*F);

  // hist (u16, 19.2 MB) aliases P1 (25.6 MB): dead until convert/gconv, which
  // run strictly after scatter on the same stream. Convert's only P1 write is
  // the sentinel row at byte offset 25.6 MB — past the hist region.
  uint16_t* hist = P1;

  k_hist<<<4*HPH*NCHK, 512, 0, stream>>>(pd_src, pd_dst, dp_src, dp_dst, hist);
  k_sumdeg2<<<SD_T0+SD_T1+SD_T2+SD_T3, 256, 0, stream>>>(
      hist, cnt_d_in, cnt_p_in, rs_p_out, rs_p_in, rs_d_out, rs_d_in, bsums);
  k_scan3b<<<NBA+NBB, 512, 0, stream>>>(cnt_d_in, N_D, cnt_p_in, N_P, bsums, off_pd, off_dp);
  k_scatter_cvt<<<NSCAT + (CVT_TOT+1)/2, 512, 0, stream>>>(
      pd_src, pd_dst, dp_src, dp_dst, off_pd, off_dp, hist, col_pd, col_dp,
      (const float4*)h_p, (const float4*)h_d, rs_p_out, rs_d_out,
      (uint2*)P0, (uint2*)D0,
      W1_pd, W1_dp, W2_pd, W2_dp, W3_pd, W3_dp, wt,
      P0 + (size_t)N_P*F, D0 + (size_t)N_D*F,
      P1 + (size_t)N_P*F, D1 + (size_t)N_D*F,
      P2 + (size_t)N_P*F, D2 + (size_t)N_D*F);

  const int gd = (N_D + 63)/64, gp = (N_P + 63)/64;
  // layer 1 (both directions fused in one dispatch)
  k_gconv2<0><<<gd+gp, 256, 0, stream>>>(
      P0, off_pd, col_pd, rs_d_in, wt + 0*F*FP, b1_pd, rs_d_out, D1, N_D, N_P, gd,
      D0, off_dp, col_dp, rs_p_in, wt + 1*F*FP, b1_dp, rs_p_out, P1, N_P, N_D);
  // layer 2
  k_gconv2<0><<<gd+gp, 256, 0, stream>>>(
      P1, off_pd, col_pd, rs_d_in, wt + 2*F*FP, b2_pd, rs_d_out, D2, N_D, N_P, gd,
      D1, off_dp, col_dp, rs_p_in, wt + 3*F*FP, b2_dp, rs_p_out, P2, N_P, N_D);
  // layer 3 (fp32 outputs: h_p3 first, then h_d3)
  k_gconv2<1><<<gd+gp, 256, 0, stream>>>(
      P2, off_pd, col_pd, rs_d_in, wt + 4*F*FP, b3_pd, nullptr, (float*)d_out + (size_t)N_P*F, N_D, N_P, gd,
      D2, off_dp, col_dp, rs_p_in, wt + 5*F*FP, b3_dp, nullptr, (float*)d_out, N_P, N_D);
}

// Round 12
// 434.177 us; speedup vs baseline: 1.0009x; 1.0009x over previous
//
#include <hip/hip_runtime.h>
#include <stdint.h>

#define N_P 100000
#define N_D 50000
#define NE  600000
#define F   128
#define FP  136   // padded LDS/global row stride (272B = 17*16B: 16B-aligned, 2-way-free banks)

// counting-sort build params (R12: NCHK=8 — fewer cross-XCD writers per col
// line; HPH=8 u16-packed hist -> 25 KB LDS)
#define NCHK   8
#define CHKE   75000                 // edges per chunk (mult of 4)
#define HPH    8                     // hist partitions (u16-packed LDS -> 25 KB)
// scatter partitions: pd=8 (N_D/8=6250), dp=16 (N_P/16=6250) -> both 25 KB
#define HPS_PD 8
#define HPS_DP 16
#define SPART  6250                  // cursor ints per scatter block (25 KB)
// hist layout (u16 elements): A0 pd_src[8][N_P] | A1 pd_dst[8][N_D] | A2 dp_src[8][N_D] | A3 dp_dst[8][N_P]
#define HOFS_A0 ((size_t)0)
#define HOFS_A1 ((size_t)NCHK*N_P)
#define HOFS_A2 ((size_t)NCHK*N_P + (size_t)NCHK*N_D)
#define HOFS_A3 ((size_t)NCHK*N_P + (size_t)2*NCHK*N_D)
// convert work units ("blocks" of 256 threads)
#define CVT_TOT (6 + (N_P+N_D)*F/4/256)   // 6 + 18750 = 18756
#define NBA 98    // scan tiles over N_D (512 nodes each)
#define NBB 196   // scan tiles over N_P
// sumdeg tiling: 256 node-pairs (=512 nodes) per block, 4 arrays
#define SD_T0 196  // arr0 (N_P) tiles
#define SD_T1 98   // arr1 (N_D)
#define SD_T2 98   // arr2 (N_D)
#define SD_T3 196  // arr3 (N_P)
#define NSCAT (HPS_PD*NCHK + HPS_DP*NCHK)   // 64 + 128 = 192 scatter blocks

typedef __attribute__((ext_vector_type(8))) __bf16 bf16x8;
typedef __attribute__((ext_vector_type(4))) float  f32x4;

static __device__ __forceinline__ float bf2f(uint16_t u){
  union{float f;uint32_t i;} v; v.i = ((uint32_t)u)<<16; return v.f;
}
static __device__ __forceinline__ uint16_t f2bf(float f){
  union{float f;uint32_t i;} v; v.f = f;
  uint32_t i = v.i;
  uint32_t r = i + 0x7fffu + ((i>>16)&1u);   // round-to-nearest-even
  return (uint16_t)(r>>16);
}

// ---------------- phase 1: per-(array, part, chunk) LDS histogram -----------
// grid = 4*HPH*NCHK = 256 blocks x 512 thr, 25 KB LDS (6 blk/CU). u16-packed
// counts in LDS AND in global (per-chunk count < 2^16: max degree ~40).
__global__ __launch_bounds__(512) void k_hist(
    const int* __restrict__ pd_src, const int* __restrict__ pd_dst,
    const int* __restrict__ dp_src, const int* __restrict__ dp_dst,
    uint16_t* __restrict__ hist){
  __shared__ uint32_t cnt[(N_P/HPH)/2];   // 6250 words = 25 KB
  const int b = blockIdx.x;
  const int arr = b >> 6, part = (b >> 3) & 7, chunk = b & 7;
  const int* src; int N; size_t hofs;
  switch(arr){
    case 0:  src = pd_src; N = N_P; hofs = HOFS_A0; break;
    case 1:  src = pd_dst; N = N_D; hofs = HOFS_A1; break;
    case 2:  src = dp_src; N = N_D; hofs = HOFS_A2; break;
    default: src = dp_dst; N = N_P; hofs = HOFS_A3; break;
  }
  const int PART = N / HPH;
  const int nw   = PART >> 1;
  const int lo   = part * PART;
  for (int i = threadIdx.x; i < nw; i += 512) cnt[i] = 0;
  __syncthreads();
  const int e0 = chunk*CHKE, e1 = min(e0 + CHKE, NE);
  const uint4* s4 = (const uint4*)(src + e0);
  const int n4 = (e1 - e0) >> 2;
  for (int i = threadIdx.x; i < n4; i += 512){
    uint4 v = s4[i];
    int a0 = (int)v.x - lo, a1 = (int)v.y - lo, a2 = (int)v.z - lo, a3 = (int)v.w - lo;
    if ((unsigned)a0 < (unsigned)PART) atomicAdd(&cnt[a0>>1], 1u << ((a0&1)<<4));
    if ((unsigned)a1 < (unsigned)PART) atomicAdd(&cnt[a1>>1], 1u << ((a1&1)<<4));
    if ((unsigned)a2 < (unsigned)PART) atomicAdd(&cnt[a2>>1], 1u << ((a2&1)<<4));
    if ((unsigned)a3 < (unsigned)PART) atomicAdd(&cnt[a3>>1], 1u << ((a3&1)<<4));
  }
  __syncthreads();
  uint32_t* out32 = (uint32_t*)(hist + hofs + (size_t)chunk*N + lo);
  for (int i = threadIdx.x; i < nw; i += 512) out32[i] = cnt[i];
}

// ------- phase 2: sumdeg + rs + FUSED scan1 (per-tile sums) -----------------
// one block per 256 node-pairs (=512 nodes) of one array; block == scan tile,
// so the in-degree tile sums reduce directly into bsums.
__global__ __launch_bounds__(256) void k_sumdeg2(
    uint16_t* __restrict__ hist,
    int* __restrict__ cnt_d_in, int* __restrict__ cnt_p_in,
    float* __restrict__ rs_p_out, float* __restrict__ rs_p_in,
    float* __restrict__ rs_d_out, float* __restrict__ rs_d_in,
    int* __restrict__ bsums){
  __shared__ int red[4];
  const int b = blockIdx.x, t = threadIdx.x;
  int arr, tile;
  if      (b < SD_T0)            { arr = 0; tile = b; }
  else if (b < SD_T0+SD_T1)      { arr = 1; tile = b - SD_T0; }
  else if (b < SD_T0+SD_T1+SD_T2){ arr = 2; tile = b - SD_T0 - SD_T1; }
  else                           { arr = 3; tile = b - SD_T0 - SD_T1 - SD_T2; }
  int N; size_t hofs; bool pre;
  switch(arr){
    case 0:  N = N_P; hofs = HOFS_A0; pre = false; break;
    case 1:  N = N_D; hofs = HOFS_A1; pre = true;  break;
    case 2:  N = N_D; hofs = HOFS_A2; pre = false; break;
    default: N = N_P; hofs = HOFS_A3; pre = true;  break;
  }
  const int npair = N >> 1;
  const int pidx  = tile*256 + t;
  int run0 = 0, run1 = 0;
  if (pidx < npair){
    uint32_t* h32 = (uint32_t*)(hist + hofs) + pidx;
    const int stride = npair;
    if (pre){
      #pragma unroll
      for (int c = 0; c < NCHK; ++c){
        uint32_t w = h32[(size_t)c*stride];
        h32[(size_t)c*stride] = (uint32_t)run0 | ((uint32_t)run1 << 16);
        run0 += (int)(w & 0xffffu); run1 += (int)(w >> 16);
      }
    } else {
      #pragma unroll
      for (int c = 0; c < NCHK; ++c){
        uint32_t w = h32[(size_t)c*stride];
        run0 += (int)(w & 0xffffu); run1 += (int)(w >> 16);
      }
    }
    const int idx = 2*pidx;
    float rs0 = rsqrtf((float)max(run0, 1));
    float rs1 = rsqrtf((float)max(run1, 1));
    switch(arr){
      case 0:  rs_p_out[idx] = rs0; rs_p_out[idx+1] = rs1; break;
      case 1:  cnt_d_in[idx] = run0; cnt_d_in[idx+1] = run1;
               rs_d_in[idx] = rs0;  rs_d_in[idx+1] = rs1;  break;
      case 2:  rs_d_out[idx] = rs0; rs_d_out[idx+1] = rs1; break;
      default: cnt_p_in[idx] = run0; cnt_p_in[idx+1] = run1;
               rs_p_in[idx] = rs0;  rs_p_in[idx+1] = rs1;  break;
    }
  }
  if (arr == 1 || arr == 3){
    int s = run0 + run1;               // 0 for out-of-range pairs
    #pragma unroll
    for (int o = 32; o; o >>= 1) s += __shfl_down(s, o, 64);
    if ((t & 63) == 0) red[t >> 6] = s;
    __syncthreads();
    if (t == 0){
      int tot = red[0] + red[1] + red[2] + red[3];
      bsums[(arr == 1) ? tile : 256 + tile] = tot;
    }
  }
}

// ------- scan3: inline scan2 (each block scans bsums seg in LDS) ------------
__global__ __launch_bounds__(512) void k_scan3b(
    const int* __restrict__ cA, int nA,
    const int* __restrict__ cB, int nB,
    const int* __restrict__ bsums,
    int* __restrict__ offA, int* __restrict__ offB){
  __shared__ int sh[512];
  __shared__ int sb[256];
  __shared__ int base_s;
  int b = blockIdx.x, t = threadIdx.x;
  const int* in; int n, bi; int* out; int seg, nb;
  if (b < NBA){ in = cA; n = nA; bi = b;       out = offA; seg = 0; nb = NBA; }
  else        { in = cB; n = nB; bi = b - NBA; out = offB; seg = 1; nb = NBB; }
  // inline inclusive scan of the bsums segment (<=256 elems); bsums unmodified
  int v0 = 0;
  if (t < 256){ v0 = (t < nb) ? bsums[seg*256 + t] : 0; sb[t] = v0; }
  __syncthreads();
  for (int ofs = 1; ofs < 256; ofs <<= 1){
    int u = 0;
    if (t < 256 && t >= ofs) u = sb[t-ofs];
    __syncthreads();
    if (t < 256) sb[t] += u;
    __syncthreads();
  }
  if (t == 0) base_s = (bi == 0) ? 0 : sb[bi-1];   // exclusive prefix
  __syncthreads();
  const int base = base_s;
  // 512-wide tile scan
  int i = bi*512 + t;
  int v = (i < n) ? in[i] : 0;
  sh[t] = v; __syncthreads();
  for (int ofs = 1; ofs < 512; ofs <<= 1){
    int u = (t >= ofs) ? sh[t-ofs] : 0; __syncthreads();
    sh[t] += u; __syncthreads();
  }
  if (i < n) out[i] = base + sh[t] - v;
  if (b == 0 && t == 0){ offA[nA] = NE; offB[nB] = NE; }
}

// ---- convert work unit: ob<6 = weight transpose + sentinel; else features ----
static __device__ __forceinline__ void convert_ob(
    int ob, int t,
    const float4* __restrict__ hp, const float4* __restrict__ hd,
    const float* __restrict__ rs_po, const float* __restrict__ rs_do,
    uint2* __restrict__ P0, uint2* __restrict__ D0,
    const float* w0,const float* w1,const float* w2,
    const float* w3,const float* w4,const float* w5,
    uint16_t* __restrict__ wt,
    uint16_t* z0, uint16_t* z1, uint16_t* z2,
    uint16_t* z3, uint16_t* z4, uint16_t* z5)
{
  if (ob < 6){
    const float* W; uint16_t* Z;
    switch(ob){ case 0:W=w0;Z=z0;break; case 1:W=w1;Z=z1;break; case 2:W=w2;Z=z2;break;
                case 3:W=w3;Z=z3;break; case 4:W=w4;Z=z4;break; default:W=w5;Z=z5; }
    uint16_t* T = wt + ob*F*FP;
    for (int idx = t; idx < F*F; idx += 256){
      int k = idx >> 7, j = idx & 127;
      T[j*FP + k] = f2bf(W[idx]);
    }
    if (t < F) Z[t] = 0;   // sentinel zero row
    return;
  }
  int i = (ob - 6)*256 + t;
  const int nP4 = N_P*F/4, nD4 = N_D*F/4;
  if (i < nP4){
    float4 v = hp[i]; float s = rs_po[i >> 5];
    uint2 r;
    r.x = ((uint32_t)f2bf(v.y*s)<<16) | f2bf(v.x*s);
    r.y = ((uint32_t)f2bf(v.w*s)<<16) | f2bf(v.z*s);
    P0[i] = r;
  } else {
    int j = i - nP4;
    if (j < nD4){
      float4 v = hd[j]; float s = rs_do[j >> 5];
      uint2 r;
      r.x = ((uint32_t)f2bf(v.y*s)<<16) | f2bf(v.x*s);
      r.y = ((uint32_t)f2bf(v.w*s)<<16) | f2bf(v.z*s);
      D0[j] = r;
    }
  }
}

// ------- phase 3 (R12): scatter FUSED with convert --------------------------
// R11 falsified the TLP theory (occ 30->42%, dur unchanged): the limiter is
// the random col[p] write path — each 64B col line was written by up to 32
// chunk-blocks on different XCDs (non-coherent L2s -> line bounce RMW;
// WRITE_SIZE showed ~4-5x col amplification). R12: NCHK=8 cuts writers/line
// 4x (per-node-chunk run 0.375->1.5 entries). srcs now read unconditionally
// as coalesced uint4 (removes gated scalar load from the store-data chain).
__global__ __launch_bounds__(512) void k_scatter_cvt(
    const int* __restrict__ pd_src, const int* __restrict__ pd_dst,
    const int* __restrict__ dp_src, const int* __restrict__ dp_dst,
    const int* __restrict__ off_pd, const int* __restrict__ off_dp,
    const uint16_t* __restrict__ hist,
    int* __restrict__ col_pd, int* __restrict__ col_dp,
    const float4* __restrict__ hp, const float4* __restrict__ hd,
    const float* __restrict__ rs_po, const float* __restrict__ rs_do,
    uint2* __restrict__ P0, uint2* __restrict__ D0,
    const float* w0,const float* w1,const float* w2,
    const float* w3,const float* w4,const float* w5,
    uint16_t* __restrict__ wt,
    uint16_t* z0, uint16_t* z1, uint16_t* z2,
    uint16_t* z3, uint16_t* z4, uint16_t* z5){
  __shared__ int base[SPART];   // 6250 ints = 25 KB
  const int b = blockIdx.x;
  if (b >= NSCAT){
    const int ob = (b - NSCAT)*2 + (threadIdx.x >> 8);
    if (ob < CVT_TOT)
      convert_ob(ob, threadIdx.x & 255, hp, hd, rs_po, rs_do, P0, D0,
                 w0,w1,w2,w3,w4,w5, wt, z0,z1,z2,z3,z4,z5);
    return;
  }
  const int* dsts; const int* srcs; const int* off; int* col; int N; size_t hofs;
  int part, chunk;
  if (b < HPS_PD*NCHK){          // pd phase: 64 blocks, HPS=8
    part = (b >> 3) & 7; chunk = b & 7;
    dsts = pd_dst; srcs = pd_src; off = off_pd; col = col_pd; N = N_D; hofs = HOFS_A1;
  } else {                       // dp phase: 128 blocks, HPS=16
    const int bb = b - HPS_PD*NCHK;
    part = (bb >> 3) & 15; chunk = bb & 7;
    dsts = dp_dst; srcs = dp_src; off = off_dp; col = col_dp; N = N_P; hofs = HOFS_A3;
  }
  const int PART = SPART;        // 6250 both phases
  const int lo = part * PART;    // even -> u32-paired hist reads OK
  const uint32_t* hc32 = (const uint32_t*)(hist + hofs + (size_t)chunk*N + lo);
  const int* offp = off + lo;
  for (int i = threadIdx.x; i < (PART>>1); i += 512){
    uint32_t w = hc32[i];
    base[2*i]   = offp[2*i]   + (int)(w & 0xffffu);
    base[2*i+1] = offp[2*i+1] + (int)(w >> 16);
  }
  __syncthreads();
  const int e0 = chunk*CHKE, e1 = min(e0 + CHKE, NE);
  const uint4* d4 = (const uint4*)(dsts + e0);
  const uint4* s4 = (const uint4*)(srcs + e0);
  const int n4 = (e1 - e0) >> 2;
  for (int i = threadIdx.x; i < n4; i += 512){
    uint4 d = d4[i];
    uint4 s = s4[i];   // unconditional coalesced read (L2-shared w/ siblings)
    int a0 = (int)d.x - lo, a1 = (int)d.y - lo, a2 = (int)d.z - lo, a3 = (int)d.w - lo;
    if ((unsigned)a0 < (unsigned)PART){ int p = atomicAdd(&base[a0], 1); col[p] = (int)s.x; }
    if ((unsigned)a1 < (unsigned)PART){ int p = atomicAdd(&base[a1], 1); col[p] = (int)s.y; }
    if ((unsigned)a2 < (unsigned)PART){ int p = atomicAdd(&base[a2], 1); col[p] = (int)s.z; }
    if ((unsigned)a3 < (unsigned)PART){ int p = atomicAdd(&base[a3], 1); col[p] = (int)s.w; }
  }
}

// ---------------- fused gconv PAIR (R1/R4 gather, 2-pass GEMM) --------------
// Gather: wave = 4 groups of 16 lanes; group g owns a row, lane l holds
// features [8l,8l+8). Broadcast all 16 col indices up front, issue ALL 8
// (16 when deg>8) plain uint4 gather loads into register arrays, THEN
// accumulate. (256,4) bounds. Counter-backed reversions: no nt loads (FETCH
// +9MB), no LDS epilogue (WRITE 75MB = layer-3 logical), no dual-stream.
// 2-pass GEMM (4 acc tiles/pass, per-pass epilogue, #pragma unroll 1).
template<int OUT_MODE>
__global__ __launch_bounds__(256, 4) void k_gconv2(
    const uint16_t* __restrict__ xA, const int* __restrict__ offAp, const int* __restrict__ colA,
    const float* __restrict__ rsA, const uint16_t* __restrict__ WtA, const float* __restrict__ biasA,
    const float* __restrict__ rsnA, void* __restrict__ outA, int ndA, int nsA, int nblkA,
    const uint16_t* __restrict__ xB, const int* __restrict__ offBp, const int* __restrict__ colB,
    const float* __restrict__ rsB, const uint16_t* __restrict__ WtB, const float* __restrict__ biasB,
    const float* __restrict__ rsnB, void* __restrict__ outB, int ndB, int nsB)
{
  __shared__ uint16_t m_lds[64*FP];    // 17408 B
  const int tid  = threadIdx.x;
  const int lane = tid & 63;
  const int wv   = tid >> 6;

  const uint16_t* x; const int* off; const int* col; const float* rs_in;
  const uint16_t* Wt; const float* bias; const float* rs_next; void* outp;
  int n_dst, zrow, bid;
  if ((int)blockIdx.x < nblkA){
    x = xA; off = offAp; col = colA; rs_in = rsA; Wt = WtA; bias = biasA;
    rs_next = rsnA; outp = outA; n_dst = ndA; zrow = nsA; bid = blockIdx.x;
  } else {
    x = xB; off = offBp; col = colB; rs_in = rsB; Wt = WtB; bias = biasB;
    rs_next = rsnB; outp = outB; n_dst = ndB; zrow = nsB; bid = blockIdx.x - nblkA;
  }

  // ---- aggregation ----
  const int row0 = bid*64 + wv*16;
  const int g    = lane >> 4;     // group
  const int l    = lane & 15;     // lane in group; features [8l, 8l+8)
  const uint16_t* xl = x + l*8;   // lane-fixed feature slice base

  int e0a[4], e1a[4], cva[4];
  #pragma unroll
  for (int i = 0; i < 4; ++i){
    int r = row0 + i*4 + g;
    bool rv = r < n_dst;
    e0a[i] = rv ? off[r]   : 0;
    e1a[i] = rv ? off[r+1] : 0;
  }
  #pragma unroll
  for (int i = 0; i < 4; ++i){
    int last = (e1a[i] > 0) ? e1a[i]-1 : 0;
    int idx  = e0a[i] + l;
    cva[i] = col[idx < e1a[i] ? idx : last];   // hoisted first batch (4 loads in flight)
  }

  #pragma unroll
  for (int i = 0; i < 4; ++i){
    int e0 = e0a[i], e1 = e1a[i];
    int cv = cva[i];
    float a0=0.f,a1=0.f,a2=0.f,a3=0.f,a4=0.f,a5=0.f,a6=0.f,a7=0.f;
    for (int e = e0; e < e1; e += 16){
      // prefetch next batch of col indices (clamped; harmless L1 re-read)
      int nidx = e + 16 + l;
      int ncv  = col[nidx < e1 ? nidx : e1-1];
      int cnt  = e1 - e;
      const bool more = (cnt > 8);
      // broadcast col indices for the whole batch up front (VALU/LDS only)
      int cb[16];
      #pragma unroll
      for (int q = 0; q < 8; ++q) cb[q] = __shfl(cv, g*16 + q, 64);
      if (more){
        #pragma unroll
        for (int q = 8; q < 16; ++q) cb[q] = __shfl(cv, g*16 + q, 64);
      }
      // issue ALL gather loads before any accumulation (max MLP)
      uint4 u[8], w[8];
      #pragma unroll
      for (int q = 0; q < 8; ++q){
        int c = (q < cnt) ? cb[q] : zrow;        // sentinel row = zeros
        u[q] = *(const uint4*)(xl + (size_t)c*F);
      }
      if (more){
        #pragma unroll
        for (int q = 8; q < 16; ++q){
          int c = (q < cnt) ? cb[q] : zrow;
          w[q-8] = *(const uint4*)(xl + (size_t)c*F);
        }
      }
      // accumulate
      #pragma unroll
      for (int q = 0; q < 8; ++q){
        a0 += bf2f((uint16_t)u[q].x); a1 += bf2f((uint16_t)(u[q].x>>16));
        a2 += bf2f((uint16_t)u[q].y); a3 += bf2f((uint16_t)(u[q].y>>16));
        a4 += bf2f((uint16_t)u[q].z); a5 += bf2f((uint16_t)(u[q].z>>16));
        a6 += bf2f((uint16_t)u[q].w); a7 += bf2f((uint16_t)(u[q].w>>16));
      }
      if (more){
        #pragma unroll
        for (int q = 0; q < 8; ++q){
          a0 += bf2f((uint16_t)w[q].x); a1 += bf2f((uint16_t)(w[q].x>>16));
          a2 += bf2f((uint16_t)w[q].y); a3 += bf2f((uint16_t)(w[q].y>>16));
          a4 += bf2f((uint16_t)w[q].z); a5 += bf2f((uint16_t)(w[q].z>>16));
          a6 += bf2f((uint16_t)w[q].w); a7 += bf2f((uint16_t)(w[q].w>>16));
        }
      }
      cv = ncv;
    }
    int r = row0 + i*4 + g;
    float rs = (r < n_dst) ? rs_in[r] : 0.f;
    uint4 pk;
    pk.x = ((uint32_t)f2bf(a1*rs)<<16) | f2bf(a0*rs);
    pk.y = ((uint32_t)f2bf(a3*rs)<<16) | f2bf(a2*rs);
    pk.z = ((uint32_t)f2bf(a5*rs)<<16) | f2bf(a4*rs);
    pk.w = ((uint32_t)f2bf(a7*rs)<<16) | f2bf(a6*rs);
    *(uint4*)&m_lds[(wv*16 + i*4 + g)*FP + l*8] = pk;
  }
  // no barrier: m_lds rows are wave-private, same-wave ds ordering is implicit

  // ---- GEMM (operand-swapped), 2 passes of 4 tiles to halve live AGPRs ----
  const int mrow = lane & 15;
  const int kgrp = lane >> 4;
  const int q4 = kgrp * 4;
  const int rr = row0 + mrow;
  const bool rv = rr < n_dst;
  const float rsn = (OUT_MODE == 0) ? (rv ? rs_next[rr] : 0.f) : 1.f;
  #pragma unroll 1
  for (int pass = 0; pass < 2; ++pass){
    f32x4 acc[4];
    #pragma unroll
    for (int t = 0; t < 4; ++t) acc[t] = (f32x4){0.f,0.f,0.f,0.f};
    #pragma unroll
    for (int k0 = 0; k0 < F; k0 += 32){
      bf16x8 bfrag = *(const bf16x8*)&m_lds[(wv*16 + mrow)*FP + k0 + kgrp*8];
      #pragma unroll
      for (int t = 0; t < 4; ++t){
        bf16x8 afrag = *(const bf16x8*)&Wt[((pass*4 + t)*16 + mrow)*FP + k0 + kgrp*8];
        acc[t] = __builtin_amdgcn_mfma_f32_16x16x32_bf16(afrag, bfrag, acc[t], 0, 0, 0);
      }
    }
    if (rv){
      #pragma unroll
      for (int t = 0; t < 4; ++t){
        const int tp = pass*4 + t;
        float4 b4 = *(const float4*)&bias[tp*16 + q4];
        float v0 = fmaxf(acc[t][0] + b4.x, 0.f);
        float v1 = fmaxf(acc[t][1] + b4.y, 0.f);
        float v2 = fmaxf(acc[t][2] + b4.z, 0.f);
        float v3 = fmaxf(acc[t][3] + b4.w, 0.f);
        if (OUT_MODE == 0){
          uint2 pk;
          pk.x = ((uint32_t)f2bf(v1*rsn)<<16) | f2bf(v0*rsn);
          pk.y = ((uint32_t)f2bf(v3*rsn)<<16) | f2bf(v2*rsn);
          *(uint2*)((uint16_t*)outp + (size_t)rr*F + tp*16 + q4) = pk;
        } else {
          float4 o; o.x = v0; o.y = v1; o.z = v2; o.w = v3;
          *(float4*)((float*)outp + (size_t)rr*F + tp*16 + q4) = o;
        }
      }
    }
  }
}

extern "C" void kernel_launch(void* const* d_in, const int* in_sizes, int n_in,
                              void* d_out, int out_size, void* d_ws, size_t ws_size,
                              hipStream_t stream) {
  const float* h_p   = (const float*)d_in[0];
  const float* h_d   = (const float*)d_in[1];
  const int* pd_src  = (const int*)d_in[2];
  const int* pd_dst  = (const int*)d_in[3];
  const int* dp_src  = (const int*)d_in[4];
  const int* dp_dst  = (const int*)d_in[5];
  const float* W1_pd = (const float*)d_in[6];   const float* b1_pd = (const float*)d_in[7];
  const float* W1_dp = (const float*)d_in[8];   const float* b1_dp = (const float*)d_in[9];
  const float* W2_pd = (const float*)d_in[10];  const float* b2_pd = (const float*)d_in[11];
  const float* W2_dp = (const float*)d_in[12];  const float* b2_dp = (const float*)d_in[13];
  const float* W3_pd = (const float*)d_in[14];  const float* b3_pd = (const float*)d_in[15];
  const float* W3_dp = (const float*)d_in[16];  const float* b3_dp = (const float*)d_in[17];

  char* w = (char*)d_ws;
  size_t o = 0;
  auto take = [&](size_t bytes)->char*{
    char* p = w + o; o += (bytes + 255) & ~(size_t)255; return p;
  };

  int* cnt_d_in  = (int*)take(4*(size_t)N_D);
  int* cnt_p_in  = (int*)take(4*(size_t)N_P);
  int* off_pd   = (int*)take(4*(size_t)(N_D+1));
  int* off_dp   = (int*)take(4*(size_t)(N_P+1));
  int* bsums    = (int*)take(4*512);
  int* col_pd   = (int*)take(4*(size_t)NE);
  int* col_dp   = (int*)take(4*(size_t)NE);
  float* rs_p_out = (float*)take(4*(size_t)N_P);
  float* rs_p_in  = (float*)take(4*(size_t)N_P);
  float* rs_d_out = (float*)take(4*(size_t)N_D);
  float* rs_d_in  = (float*)take(4*(size_t)N_D);
  uint16_t* wt  = (uint16_t*)take(2*(size_t)6*F*FP);
  // feature buffers have n+1 rows; row n is the zeroed sentinel
  uint16_t* P0  = (uint16_t*)take(2*(size_t)(N_P+1)*F);
  uint16_t* P1  = (uint16_t*)take(2*(size_t)(N_P+1)*F);
  uint16_t* P2  = (uint16_t*)take(2*(size_t)(N_P+1)*F);
  uint16_t* D0  = (uint16_t*)take(2*(size_t)(N_D+1)*F);
  uint16_t* D1  = (uint16_t*)take(2*(size_t)(N_D+1)*F);
  uint16_t* D2  = (uint16_t*)take(2*(size_t)(N_D+1)*F);

  // hist (u16, 4.8 MB @ NCHK=8) aliases P1 (25.6 MB): dead until convert/
  // gconv, which run strictly after scatter on the same stream. Convert's
  // only P1 write is the sentinel row at byte offset 25.6 MB.
  uint16_t* hist = P1;

  k_hist<<<4*HPH*NCHK, 512, 0, stream>>>(pd_src, pd_dst, dp_src, dp_dst, hist);
  k_sumdeg2<<<SD_T0+SD_T1+SD_T2+SD_T3, 256, 0, stream>>>(
      hist, cnt_d_in, cnt_p_in, rs_p_out, rs_p_in, rs_d_out, rs_d_in, bsums);
  k_scan3b<<<NBA+NBB, 512, 0, stream>>>(cnt_d_in, N_D, cnt_p_in, N_P, bsums, off_pd, off_dp);
  k_scatter_cvt<<<NSCAT + (CVT_TOT+1)/2, 512, 0, stream>>>(
      pd_src, pd_dst, dp_src, dp_dst, off_pd, off_dp, hist, col_pd, col_dp,
      (const float4*)h_p, (const float4*)h_d, rs_p_out, rs_d_out,
      (uint2*)P0, (uint2*)D0,
      W1_pd, W1_dp, W2_pd, W2_dp, W3_pd, W3_dp, wt,
      P0 + (size_t)N_P*F, D0 + (size_t)N_D*F,
      P1 + (size_t)N_P*F, D1 + (size_t)N_D*F,
      P2 + (size_t)N_P*F, D2 + (size_t)N_D*F);

  const int gd = (N_D + 63)/64, gp = (N_P + 63)/64;
  // layer 1 (both directions fused in one dispatch)
  k_gconv2<0><<<gd+gp, 256, 0, stream>>>(
      P0, off_pd, col_pd, rs_d_in, wt + 0*F*FP, b1_pd, rs_d_out, D1, N_D, N_P, gd,
      D0, off_dp, col_dp, rs_p_in, wt + 1*F*FP, b1_dp, rs_p_out, P1, N_P, N_D);
  // layer 2
  k_gconv2<0><<<gd+gp, 256, 0, stream>>>(
      P1, off_pd, col_pd, rs_d_in, wt + 2*F*FP, b2_pd, rs_d_out, D2, N_D, N_P, gd,
      D1, off_dp, col_dp, rs_p_in, wt + 3*F*FP, b2_dp, rs_p_out, P2, N_P, N_D);
  // layer 3 (fp32 outputs: h_p3 first, then h_d3)
  k_gconv2<1><<<gd+gp, 256, 0, stream>>>(
      P2, off_pd, col_pd, rs_d_in, wt + 4*F*FP, b3_pd, nullptr, (float*)d_out + (size_t)N_P*F, N_D, N_P, gd,
      D2, off_dp, col_dp, rs_p_in, wt + 5*F*FP, b3_dp, nullptr, (float*)d_out, N_P, N_D);
}